// Round 4
// baseline (330.294 us; speedup 1.0000x reference)
//
#include <hip/hip_runtime.h>

// Problem constants
#define BSEQ 64
#define LSEQ 512
#define CCH  1024
#define NT   7            // NUM_TAGS
#define NC   5            // real classes (labels are always 0..4)
#define NTOK (BSEQ*LSEQ)  // 32768
#define START_TAG 5
#define STOP_TAG  6
#define NEGV (-10000.0f)
#define GRID_LOGITS 1024  // k_logits assumes exactly this grid (8 rows/wave)

typedef float vfloat4 __attribute__((ext_vector_type(4)));

// ---------------- DPP wave64 sum (result lands in lane 63) ----------------
template<int CTRL, int RMASK, int BMASK>
__device__ __forceinline__ float dpp_add(float x) {
    int y = __builtin_amdgcn_update_dpp(0, __float_as_int(x), CTRL, RMASK, BMASK, true);
    return x + __int_as_float(y);
}
__device__ __forceinline__ float wave_sum(float x) {
    x = dpp_add<0x111, 0xF, 0xF>(x);  // row_shr:1
    x = dpp_add<0x112, 0xF, 0xF>(x);  // row_shr:2
    x = dpp_add<0x114, 0xF, 0xF>(x);  // row_shr:4
    x = dpp_add<0x118, 0xF, 0xF>(x);  // row_shr:8  -> lane15 of each row16 has row sum
    x = dpp_add<0x142, 0xA, 0xF>(x);  // row_bcast:15 into rows 1,3
    x = dpp_add<0x143, 0xC, 0xF>(x);  // row_bcast:31 into rows 2,3 -> lane63 = total
    return x;
}

// 5-way log-sum-exp helper
__device__ __forceinline__ float lse5(const float v0, const float v1, const float v2,
                                      const float v3, const float v4) {
    float m = fmaxf(fmaxf(fmaxf(v0, v1), fmaxf(v2, v3)), v4);
    float s = __expf(v0 - m) + __expf(v1 - m) + __expf(v2 - m)
            + __expf(v3 - m) + __expf(v4 - m);
    return m + __logf(s);
}

// ---------------- Kernel 1: logits (X @ W^T + b), labels copy, score zero ----------------
// R7: MEASUREMENT ROUND. Kernel body byte-identical to R6 (phase-outer,
// W-in-VGPR, NT loads, 3-slot rolling prefetch). The launch sequence runs
// k_logits 5x (idempotent: all writes are deterministic pure functions of the
// inputs) so tL = (dur - dur_R3)/4 with fill noise divided by 4. This pins
// whether k_logits is ~45us (18-24us headroom vs the 21us stream floor /
// 26us RMSNorm-class 4.9TB/s point) or already at the floor -- every edit so
// far has been judged through ~158us of harness fills + noise.
__global__ __launch_bounds__(256)
void k_logits(const float* __restrict__ X, const float* __restrict__ W,
              const float* __restrict__ bvec, const int* __restrict__ lab,
              float* __restrict__ out)
{
    __shared__ float Wl[NT][CCH];   // 28 KB
    __shared__ float bl[NT];

    const int lane = threadIdx.x & 63;
    const int wid  = (blockIdx.x * 256 + threadIdx.x) >> 6;   // 0..4095
    const int nw   = (GRID_LOGITS * 256) >> 6;                // 4096 waves

    vfloat4 xb[3][4];   // [phase-slot][row j] -- all indices static after unroll

    // phase p (0..7): group G=p>>2 (rows wid+(G*4+j)*nw), channel chunk k=p&3.
    // issue loads for phase p into slot p%3.
    #define ISSUE_PHASE(p, slot)                                                   \
        if ((p) < 8) {                                                             \
            const int G_ = (p) >> 2, k_ = (p) & 3;                                 \
            _Pragma("unroll")                                                      \
            for (int j = 0; j < 4; j++) {                                          \
                const size_t row_ = (size_t)(wid + (G_*4 + j) * nw);               \
                const vfloat4* xp_ = (const vfloat4*)(X + row_ * CCH) + (k_*64 + lane); \
                xb[slot][j] = __builtin_nontemporal_load(xp_);                     \
            }                                                                      \
        }

    // prologue: phases 0,1 in flight before W staging; barrier drain covers both
    ISSUE_PHASE(0, 0)
    ISSUE_PHASE(1, 1)

    {
        const vfloat4* W4  = (const vfloat4*)W;
        vfloat4*       Wl4 = (vfloat4*)(&Wl[0][0]);
        for (int i = threadIdx.x; i < NT*CCH/4; i += 256) Wl4[i] = W4[i];
        if (threadIdx.x < NT) bl[threadIdx.x] = bvec[threadIdx.x];
    }
    __syncthreads();

    float* outP = out + 1 + NTOK;

    float acc[4][NT];
    #pragma unroll
    for (int j = 0; j < 4; j++)
        #pragma unroll
        for (int t = 0; t < NT; t++) acc[j][t] = 0.0f;

    #pragma unroll
    for (int p = 0; p < 8; ++p) {
        const int slot = p % 3;
        const int k    = p & 3;

        // prefetch phase p+2 into slot (p+2)%3 (holds phase p-1, consumed)
        ISSUE_PHASE(p + 2, (p + 2) % 3)

        // hoist this phase's W fragments into registers (7 ds_read_b128)
        vfloat4 wreg[NT];
        {
            const int cb = (k*64 + lane) * 4;
            #pragma unroll
            for (int t = 0; t < NT; t++)
                wreg[t] = *(const vfloat4*)(&Wl[t][cb]);   // unit-stride, conflict-free
        }

        // pure-register inner loop: 4 rows x 7 tags x 4 FMA
        #pragma unroll
        for (int j = 0; j < 4; j++) {
            #pragma unroll
            for (int t = 0; t < NT; t++) {
                acc[j][t] = fmaf(xb[slot][j].x, wreg[t].x,
                            fmaf(xb[slot][j].y, wreg[t].y,
                            fmaf(xb[slot][j].z, wreg[t].z,
                            fmaf(xb[slot][j].w, wreg[t].w, acc[j][t]))));
            }
        }

        // end of a row-group (k==3): reduce + store + reset acc
        if (k == 3) {
            const int G = p >> 2;
            #pragma unroll
            for (int j = 0; j < 4; j++) {
                const size_t row = (size_t)(wid + (G*4 + j) * nw);
                #pragma unroll
                for (int t = 0; t < NT; t++) {
                    float s = wave_sum(acc[j][t]);
                    if (lane == 63) outP[row * NT + t] = s + bl[t];
                    acc[j][t] = 0.0f;
                }
            }
        }
    }
    #undef ISSUE_PHASE

    // labels as float + zero the score slot
    for (int i = blockIdx.x * 256 + threadIdx.x; i < NTOK; i += GRID_LOGITS * 256)
        out[1 + i] = (float)lab[i];
    if (blockIdx.x == 0 && threadIdx.x == 0) out[0] = 0.0f;
}

// ---------------- Kernel 2: CRF NLL, 5-class log-semiring chunked scan ----------------
// (unchanged; launched once -- atomicAdd is not idempotent.)
__global__ __launch_bounds__(320)
void k_crf(const float* __restrict__ dout_ro, const int* __restrict__ lab,
           const float* __restrict__ trans, float* __restrict__ score)
{
    __shared__ float E[LSEQ*NT];   // 3584 floats; reused as matrix buffer A after recurrence
    __shared__ float M2[32*25];    // ping-pong buffer B
    __shared__ float T[49];
    __shared__ float u_sh[NC];     // fv after step 0 (START injection)
    __shared__ float gred[5];

    const int b   = blockIdx.x;
    const int tid = threadIdx.x;
    const float* feats = dout_ro + 1 + NTOK + (size_t)b * (LSEQ*NT);

    for (int i = tid; i < LSEQ*NT; i += 320) E[i] = feats[i];
    if (tid < 49) T[tid] = trans[tid];
    __syncthreads();

    if (tid < NC) u_sh[tid] = T[tid*NT + START_TAG] + E[tid];   // e0[k] before E is overwritten

    // ---- gold score (parallel over tokens) ----
    float g = 0.0f;
    for (int l = tid; l < LSEQ; l += 320) {
        const int t  = lab[b*LSEQ + l];
        const int tp = (l == 0) ? START_TAG : lab[b*LSEQ + l - 1];
        g += E[l*NT + t] + T[t*NT + tp];
    }
    if (tid == 0) g += T[STOP_TAG*NT + lab[b*LSEQ + LSEQ - 1]];
    {
        float gs = wave_sum(g);
        if ((tid & 63) == 63) gred[tid >> 6] = gs;
    }

    // ---- chunk basis recurrences (5x5, all in registers) ----
    float TR[NC*NC];
    #pragma unroll
    for (int j = 0; j < NC; j++)
        #pragma unroll
        for (int k = 0; k < NC; k++) TR[j*NC + k] = T[j*NT + k];

    const int chunk = tid / NC;
    const int basis = tid - chunk * NC;
    float fv[NC];
    #pragma unroll
    for (int j = 0; j < NC; j++) fv[j] = (j == basis) ? 0.0f : NEGV;

    const int l0    = (chunk == 0) ? 1 : chunk * 8;
    const int steps = (chunk == 0) ? 7 : 8;
    for (int s = 0; s < steps; s++) {
        const int l = l0 + s;
        float fn[NC];
        #pragma unroll
        for (int j = 0; j < NC; j++) {
            fn[j] = lse5(fv[0] + TR[j*NC+0], fv[1] + TR[j*NC+1], fv[2] + TR[j*NC+2],
                         fv[3] + TR[j*NC+3], fv[4] + TR[j*NC+4]) + E[l*NT + j];
        }
        #pragma unroll
        for (int j = 0; j < NC; j++) fv[j] = fn[j];
    }
    __syncthreads();   // all E reads done; safe to overwrite with matrices
    #pragma unroll
    for (int j = 0; j < NC; j++) E[chunk*25 + basis*NC + j] = fv[j];

    // ---- tree combine: C[i][j] = lse_k(A[i][k] + B[k][j]), chronological L->R ----
    int n = 64, cur = 0;
    while (n > 1) {
        __syncthreads();
        const float* in = (cur == 0) ? (const float*)E : (const float*)M2;
        float*       ob = (cur == 0) ? M2 : E;
        const int half = n >> 1;
        for (int e2 = tid; e2 < half*25; e2 += 320) {
            const int p = e2 / 25, r = e2 - p*25;
            const int i = r / NC, j = r - (r/NC)*NC;
            const float* A  = in + (2*p)*25 + i*NC;
            const float* Bm = in + (2*p + 1)*25 + j;
            ob[p*25 + r] = lse5(A[0] + Bm[0], A[1] + Bm[NC], A[2] + Bm[2*NC],
                                A[3] + Bm[3*NC], A[4] + Bm[4*NC]);
        }
        cur ^= 1; n = half;
    }
    __syncthreads();

    if (tid == 0) {
        float gg = gred[0] + gred[1] + gred[2] + gred[3] + gred[4];
        const float* M = (cur == 0) ? (const float*)E : (const float*)M2;  // final 5x5
        float v[NC];
        #pragma unroll
        for (int j = 0; j < NC; j++)
            v[j] = lse5(u_sh[0] + M[0*NC+j], u_sh[1] + M[1*NC+j], u_sh[2] + M[2*NC+j],
                        u_sh[3] + M[3*NC+j], u_sh[4] + M[4*NC+j]);
        float fwd = lse5(v[0] + T[STOP_TAG*NT+0], v[1] + T[STOP_TAG*NT+1],
                         v[2] + T[STOP_TAG*NT+2], v[3] + T[STOP_TAG*NT+3],
                         v[4] + T[STOP_TAG*NT+4]);
        atomicAdd(score, fwd - gg);
    }
}

extern "C" void kernel_launch(void* const* d_in, const int* in_sizes, int n_in,
                              void* d_out, int out_size, void* d_ws, size_t ws_size,
                              hipStream_t stream) {
    const float* X     = (const float*)d_in[0];   // fuse_embeddings [32768,1024]
    const int*   lab   = (const int*)  d_in[1];   // label_class [32768]
    const float* W     = (const float*)d_in[2];   // [7,1024]
    const float* bvec  = (const float*)d_in[3];   // [7]
    const float* trans = (const float*)d_in[4];   // [7,7]
    float* out = (float*)d_out;

    // R7 measurement: 5x k_logits (idempotent) -> tL = (dur - dur_R3)/4.
    k_logits<<<GRID_LOGITS, 256, 0, stream>>>(X, W, bvec, lab, out);
    k_logits<<<GRID_LOGITS, 256, 0, stream>>>(X, W, bvec, lab, out);
    k_logits<<<GRID_LOGITS, 256, 0, stream>>>(X, W, bvec, lab, out);
    k_logits<<<GRID_LOGITS, 256, 0, stream>>>(X, W, bvec, lab, out);
    k_logits<<<GRID_LOGITS, 256, 0, stream>>>(X, W, bvec, lab, out);
    k_crf<<<BSEQ, 320, 0, stream>>>(out, lab, trans, out);
}

// Round 5
// 305.927 us; speedup vs baseline: 1.0797x; 1.0797x over previous
//
#include <hip/hip_runtime.h>

// Problem constants
#define BSEQ 64
#define LSEQ 512
#define CCH  1024
#define NT   7            // NUM_TAGS
#define NC   5            // real classes (labels are always 0..4)
#define NTOK (BSEQ*LSEQ)  // 32768
#define START_TAG 5
#define STOP_TAG  6
#define NEGV (-10000.0f)
#define GRID_LOGITS 1024  // k_logits assumes exactly this grid (8 rows/wave)

typedef float vfloat4 __attribute__((ext_vector_type(4)));

// ---------------- DPP wave64 sum (result lands in lane 63) ----------------
template<int CTRL, int RMASK, int BMASK>
__device__ __forceinline__ float dpp_add(float x) {
    int y = __builtin_amdgcn_update_dpp(0, __float_as_int(x), CTRL, RMASK, BMASK, true);
    return x + __int_as_float(y);
}
__device__ __forceinline__ float wave_sum(float x) {
    x = dpp_add<0x111, 0xF, 0xF>(x);  // row_shr:1
    x = dpp_add<0x112, 0xF, 0xF>(x);  // row_shr:2
    x = dpp_add<0x114, 0xF, 0xF>(x);  // row_shr:4
    x = dpp_add<0x118, 0xF, 0xF>(x);  // row_shr:8  -> lane15 of each row16 has row sum
    x = dpp_add<0x142, 0xA, 0xF>(x);  // row_bcast:15 into rows 1,3
    x = dpp_add<0x143, 0xC, 0xF>(x);  // row_bcast:31 into rows 2,3 -> lane63 = total
    return x;
}

// 5-way log-sum-exp helper
__device__ __forceinline__ float lse5(const float v0, const float v1, const float v2,
                                      const float v3, const float v4) {
    float m = fmaxf(fmaxf(fmaxf(v0, v1), fmaxf(v2, v3)), v4);
    float s = __expf(v0 - m) + __expf(v1 - m) + __expf(v2 - m)
            + __expf(v3 - m) + __expf(v4 - m);
    return m + __logf(s);
}

// ---------------- Kernel 1: logits (X @ W^T + b), labels copy, score zero ----------------
// R8: byte-identical to R6/R7 body. R7 measured tL+gap = 29.1 us/launch
// (116.3/4) -> k_logits is at 4.4-5.8 TB/s, i.e. within ~8 us of the 6.3 TB/s
// stream floor (20-21 us). NOT the main remaining prize.
__global__ __launch_bounds__(256)
void k_logits(const float* __restrict__ X, const float* __restrict__ W,
              const float* __restrict__ bvec, const int* __restrict__ lab,
              float* __restrict__ out)
{
    __shared__ float Wl[NT][CCH];   // 28 KB
    __shared__ float bl[NT];

    const int lane = threadIdx.x & 63;
    const int wid  = (blockIdx.x * 256 + threadIdx.x) >> 6;   // 0..4095
    const int nw   = (GRID_LOGITS * 256) >> 6;                // 4096 waves

    vfloat4 xb[3][4];   // [phase-slot][row j] -- all indices static after unroll

    #define ISSUE_PHASE(p, slot)                                                   \
        if ((p) < 8) {                                                             \
            const int G_ = (p) >> 2, k_ = (p) & 3;                                 \
            _Pragma("unroll")                                                      \
            for (int j = 0; j < 4; j++) {                                          \
                const size_t row_ = (size_t)(wid + (G_*4 + j) * nw);               \
                const vfloat4* xp_ = (const vfloat4*)(X + row_ * CCH) + (k_*64 + lane); \
                xb[slot][j] = __builtin_nontemporal_load(xp_);                     \
            }                                                                      \
        }

    // prologue: phases 0,1 in flight before W staging; barrier drain covers both
    ISSUE_PHASE(0, 0)
    ISSUE_PHASE(1, 1)

    {
        const vfloat4* W4  = (const vfloat4*)W;
        vfloat4*       Wl4 = (vfloat4*)(&Wl[0][0]);
        for (int i = threadIdx.x; i < NT*CCH/4; i += 256) Wl4[i] = W4[i];
        if (threadIdx.x < NT) bl[threadIdx.x] = bvec[threadIdx.x];
    }
    __syncthreads();

    float* outP = out + 1 + NTOK;

    float acc[4][NT];
    #pragma unroll
    for (int j = 0; j < 4; j++)
        #pragma unroll
        for (int t = 0; t < NT; t++) acc[j][t] = 0.0f;

    #pragma unroll
    for (int p = 0; p < 8; ++p) {
        const int slot = p % 3;
        const int k    = p & 3;

        ISSUE_PHASE(p + 2, (p + 2) % 3)

        vfloat4 wreg[NT];
        {
            const int cb = (k*64 + lane) * 4;
            #pragma unroll
            for (int t = 0; t < NT; t++)
                wreg[t] = *(const vfloat4*)(&Wl[t][cb]);   // unit-stride, conflict-free
        }

        #pragma unroll
        for (int j = 0; j < 4; j++) {
            #pragma unroll
            for (int t = 0; t < NT; t++) {
                acc[j][t] = fmaf(xb[slot][j].x, wreg[t].x,
                            fmaf(xb[slot][j].y, wreg[t].y,
                            fmaf(xb[slot][j].z, wreg[t].z,
                            fmaf(xb[slot][j].w, wreg[t].w, acc[j][t]))));
            }
        }

        if (k == 3) {
            const int G = p >> 2;
            #pragma unroll
            for (int j = 0; j < 4; j++) {
                const size_t row = (size_t)(wid + (G*4 + j) * nw);
                #pragma unroll
                for (int t = 0; t < NT; t++) {
                    float s = wave_sum(acc[j][t]);
                    if (lane == 63) outP[row * NT + t] = s + bl[t];
                    acc[j][t] = 0.0f;
                }
            }
        }
    }
    #undef ISSUE_PHASE

    // labels as float + zero the score slot
    for (int i = blockIdx.x * 256 + threadIdx.x; i < NTOK; i += GRID_LOGITS * 256)
        out[1 + i] = (float)lab[i];
    if (blockIdx.x == 0 && threadIdx.x == 0) out[0] = 0.0f;
}

// ---------------- Kernel 2: CRF NLL, 5-class log-semiring chunked scan ----------------
// R8: MEASUREMENT. `real` flag: dummy launches (real=0) do ALL the same work
// but skip the final atomicAdd (no global writes -> idempotent, safe to
// replicate). 8 dummies + 1 real => dur = base + 8*(tC + gap), disambiguating
// {k_crf slow} vs {launch-boundary overhead} vs {fixed window overhead}.
__global__ __launch_bounds__(320)
void k_crf(const float* __restrict__ dout_ro, const int* __restrict__ lab,
           const float* __restrict__ trans, float* __restrict__ score,
           const int real)
{
    __shared__ float E[LSEQ*NT];   // 3584 floats; reused as matrix buffer A after recurrence
    __shared__ float M2[32*25];    // ping-pong buffer B
    __shared__ float T[49];
    __shared__ float u_sh[NC];     // fv after step 0 (START injection)
    __shared__ float gred[5];

    const int b   = blockIdx.x;
    const int tid = threadIdx.x;
    const float* feats = dout_ro + 1 + NTOK + (size_t)b * (LSEQ*NT);

    for (int i = tid; i < LSEQ*NT; i += 320) E[i] = feats[i];
    if (tid < 49) T[tid] = trans[tid];
    __syncthreads();

    if (tid < NC) u_sh[tid] = T[tid*NT + START_TAG] + E[tid];   // e0[k] before E is overwritten

    // ---- gold score (parallel over tokens) ----
    float g = 0.0f;
    for (int l = tid; l < LSEQ; l += 320) {
        const int t  = lab[b*LSEQ + l];
        const int tp = (l == 0) ? START_TAG : lab[b*LSEQ + l - 1];
        g += E[l*NT + t] + T[t*NT + tp];
    }
    if (tid == 0) g += T[STOP_TAG*NT + lab[b*LSEQ + LSEQ - 1]];
    {
        float gs = wave_sum(g);
        if ((tid & 63) == 63) gred[tid >> 6] = gs;
    }

    // ---- chunk basis recurrences (5x5, all in registers) ----
    float TR[NC*NC];
    #pragma unroll
    for (int j = 0; j < NC; j++)
        #pragma unroll
        for (int k = 0; k < NC; k++) TR[j*NC + k] = T[j*NT + k];

    const int chunk = tid / NC;
    const int basis = tid - chunk * NC;
    float fv[NC];
    #pragma unroll
    for (int j = 0; j < NC; j++) fv[j] = (j == basis) ? 0.0f : NEGV;

    const int l0    = (chunk == 0) ? 1 : chunk * 8;
    const int steps = (chunk == 0) ? 7 : 8;
    for (int s = 0; s < steps; s++) {
        const int l = l0 + s;
        float fn[NC];
        #pragma unroll
        for (int j = 0; j < NC; j++) {
            fn[j] = lse5(fv[0] + TR[j*NC+0], fv[1] + TR[j*NC+1], fv[2] + TR[j*NC+2],
                         fv[3] + TR[j*NC+3], fv[4] + TR[j*NC+4]) + E[l*NT + j];
        }
        #pragma unroll
        for (int j = 0; j < NC; j++) fv[j] = fn[j];
    }
    __syncthreads();   // all E reads done; safe to overwrite with matrices
    #pragma unroll
    for (int j = 0; j < NC; j++) E[chunk*25 + basis*NC + j] = fv[j];

    // ---- tree combine: C[i][j] = lse_k(A[i][k] + B[k][j]), chronological L->R ----
    int n = 64, cur = 0;
    while (n > 1) {
        __syncthreads();
        const float* in = (cur == 0) ? (const float*)E : (const float*)M2;
        float*       ob = (cur == 0) ? M2 : E;
        const int half = n >> 1;
        for (int e2 = tid; e2 < half*25; e2 += 320) {
            const int p = e2 / 25, r = e2 - p*25;
            const int i = r / NC, j = r - (r/NC)*NC;
            const float* A  = in + (2*p)*25 + i*NC;
            const float* Bm = in + (2*p + 1)*25 + j;
            ob[p*25 + r] = lse5(A[0] + Bm[0], A[1] + Bm[NC], A[2] + Bm[2*NC],
                                A[3] + Bm[3*NC], A[4] + Bm[4*NC]);
        }
        cur ^= 1; n = half;
    }
    __syncthreads();

    if (tid == 0) {
        float gg = gred[0] + gred[1] + gred[2] + gred[3] + gred[4];
        const float* M = (cur == 0) ? (const float*)E : (const float*)M2;  // final 5x5
        float v[NC];
        #pragma unroll
        for (int j = 0; j < NC; j++)
            v[j] = lse5(u_sh[0] + M[0*NC+j], u_sh[1] + M[1*NC+j], u_sh[2] + M[2*NC+j],
                        u_sh[3] + M[3*NC+j], u_sh[4] + M[4*NC+j]);
        float fwd = lse5(v[0] + T[STOP_TAG*NT+0], v[1] + T[STOP_TAG*NT+1],
                         v[2] + T[STOP_TAG*NT+2], v[3] + T[STOP_TAG*NT+3],
                         v[4] + T[STOP_TAG*NT+4]);
        if (real) atomicAdd(score, fwd - gg);
    }
}

extern "C" void kernel_launch(void* const* d_in, const int* in_sizes, int n_in,
                              void* d_out, int out_size, void* d_ws, size_t ws_size,
                              hipStream_t stream) {
    const float* X     = (const float*)d_in[0];   // fuse_embeddings [32768,1024]
    const int*   lab   = (const int*)  d_in[1];   // label_class [32768]
    const float* W     = (const float*)d_in[2];   // [7,1024]
    const float* bvec  = (const float*)d_in[3];   // [7]
    const float* trans = (const float*)d_in[4];   // [7,7]
    float* out = (float*)d_out;

    k_logits<<<GRID_LOGITS, 256, 0, stream>>>(X, W, bvec, lab, out);
    // R8 measurement: 8 dummy k_crf (no atomic, idempotent) + 1 real.
    // dur = base + 8*(tC + gap).
    for (int i = 0; i < 8; i++)
        k_crf<<<BSEQ, 320, 0, stream>>>(out, lab, trans, out, 0);
    k_crf<<<BSEQ, 320, 0, stream>>>(out, lab, trans, out, 1);
}

// Round 6
// 211.694 us; speedup vs baseline: 1.5602x; 1.4451x over previous
//
#include <hip/hip_runtime.h>
#include <hip/hip_cooperative_groups.h>

namespace cg = cooperative_groups;

// Problem constants
#define BSEQ 64
#define LSEQ 512
#define CCH  1024
#define NT   7            // NUM_TAGS
#define NC   5            // real classes (labels are always 0..4)
#define NTOK (BSEQ*LSEQ)  // 32768
#define START_TAG 5
#define STOP_TAG  6
#define NEGV (-10000.0f)
#define GRID_LOGITS 1024  // fallback k_logits grid
#define FGRID 1024        // fused grid: 4 blocks/CU on 256 CUs (co-resident)
#define FBLK  256

// workspace layout (floats)
#define WS_M   0          // [1024][32] chunk matrices (25 used per chunk)
#define WS_G   32768      // [1024] gold partials
#define WS_U   33792      // [64][8] u vectors (5 used)
#define WS_TOT 34304

typedef float vfloat4 __attribute__((ext_vector_type(4)));

// ---------------- DPP wave64 sum (result lands in lane 63) ----------------
template<int CTRL, int RMASK, int BMASK>
__device__ __forceinline__ float dpp_add(float x) {
    int y = __builtin_amdgcn_update_dpp(0, __float_as_int(x), CTRL, RMASK, BMASK, true);
    return x + __int_as_float(y);
}
__device__ __forceinline__ float wave_sum(float x) {
    x = dpp_add<0x111, 0xF, 0xF>(x);  // row_shr:1
    x = dpp_add<0x112, 0xF, 0xF>(x);  // row_shr:2
    x = dpp_add<0x114, 0xF, 0xF>(x);  // row_shr:4
    x = dpp_add<0x118, 0xF, 0xF>(x);  // row_shr:8
    x = dpp_add<0x142, 0xA, 0xF>(x);  // row_bcast:15 into rows 1,3
    x = dpp_add<0x143, 0xC, 0xF>(x);  // row_bcast:31 into rows 2,3 -> lane63 = total
    return x;
}

// 5-way log-sum-exp helper
__device__ __forceinline__ float lse5(const float v0, const float v1, const float v2,
                                      const float v3, const float v4) {
    float m = fmaxf(fmaxf(fmaxf(v0, v1), fmaxf(v2, v3)), v4);
    float s = __expf(v0 - m) + __expf(v1 - m) + __expf(v2 - m)
            + __expf(v3 - m) + __expf(v4 - m);
    return m + __logf(s);
}

// ================= FUSED kernel (cooperative) =================
// R9: R7/R8 measurements solved the decomposition: per-dispatch boundary
// g=8.7us, tL=20.4us (= EXACT 6.3TB/s stream floor -> logits untouchable),
// tC=2.8us. Only controllable item: the kL->kC boundary + tC. Fuse:
//  - 1024 blocks x 256 thr (4 blocks/CU co-resident; logits structure is the
//    proven floor-hitting one, row mapping changed so block bx owns 32
//    CONTIGUOUS rows = one 32-step CRF chunk of batch bx/16).
//  - per block: logits -> E to LDS -> chunk matrix (4x 8-step basis
//    recurrences, in-wave tree) + gold partial + u (sub==0) -> ws.
//  - ONE grid.sync(); blocks 0..63 fold u o M0..M15, add STOP, atomicAdd
//    score into out[0] (atomicExch-zeroed by block 0 pre-sync).
__global__ __launch_bounds__(256)
void k_fused(const float* __restrict__ X, const float* __restrict__ W,
             const float* __restrict__ bvec, const int* __restrict__ lab,
             const float* __restrict__ trans, float* __restrict__ out,
             float* __restrict__ ws)
{
    __shared__ float Wl[NT][CCH];   // 28 KB
    __shared__ float bl[NT];
    __shared__ float Tl[49];
    __shared__ float E_lds[32][5];  // this block's emissions (classes 0..4, incl bias)
    __shared__ float Msub[4*25];    // 4 sub-chunk matrices
    __shared__ float Cb[2*25];      // combine round 1
    __shared__ float Mbuf[16*25];   // fold prefetch (batch's 16 chunk matrices)

    const int tid  = threadIdx.x;
    const int lane = tid & 63;
    const int wv   = tid >> 6;      // 0..3
    const int bx   = blockIdx.x;

    if (bx == 0 && tid == 0) atomicExch(out, 0.0f);  // score base; all adds post-sync

    vfloat4 xb[3][4];   // [phase-slot][row j]
    const size_t rbase = (size_t)bx * 32 + wv;       // + m*4, m=0..7

    // phase p (0..7): row-group G=p>>2 (rows rbase+(G*4+j)*4), channel chunk k=p&3
    #define ISSUE_PHASE(p, slot)                                                    \
        if ((p) < 8) {                                                              \
            const int G_ = (p) >> 2, k_ = (p) & 3;                                  \
            _Pragma("unroll")                                                       \
            for (int j = 0; j < 4; j++) {                                           \
                const size_t row_ = rbase + (size_t)((G_*4 + j) * 4);               \
                const vfloat4* xp_ = (const vfloat4*)(X + row_ * CCH) + (k_*64 + lane); \
                xb[slot][j] = __builtin_nontemporal_load(xp_);                      \
            }                                                                       \
        }

    ISSUE_PHASE(0, 0)
    ISSUE_PHASE(1, 1)

    {
        const vfloat4* W4  = (const vfloat4*)W;
        vfloat4*       Wl4 = (vfloat4*)(&Wl[0][0]);
        for (int i = tid; i < NT*CCH/4; i += FBLK) Wl4[i] = W4[i];
        if (tid < NT) bl[tid] = bvec[tid];
        if (tid < 49) Tl[tid] = trans[tid];
        const int gidx = bx * FBLK + tid;            // labels copy (blocks 0..127)
        if (gidx < NTOK) out[1 + gidx] = (float)lab[gidx];
    }
    __syncthreads();

    float* outP = out + 1 + NTOK;

    float acc[4][NT];
    #pragma unroll
    for (int j = 0; j < 4; j++)
        #pragma unroll
        for (int t = 0; t < NT; t++) acc[j][t] = 0.0f;

    #pragma unroll
    for (int p = 0; p < 8; ++p) {
        const int slot = p % 3;
        const int k    = p & 3;

        ISSUE_PHASE(p + 2, (p + 2) % 3)

        vfloat4 wreg[NT];
        {
            const int cb = (k*64 + lane) * 4;
            #pragma unroll
            for (int t = 0; t < NT; t++)
                wreg[t] = *(const vfloat4*)(&Wl[t][cb]);
        }

        #pragma unroll
        for (int j = 0; j < 4; j++) {
            #pragma unroll
            for (int t = 0; t < NT; t++) {
                acc[j][t] = fmaf(xb[slot][j].x, wreg[t].x,
                            fmaf(xb[slot][j].y, wreg[t].y,
                            fmaf(xb[slot][j].z, wreg[t].z,
                            fmaf(xb[slot][j].w, wreg[t].w, acc[j][t]))));
            }
        }

        if (k == 3) {
            const int G = p >> 2;
            #pragma unroll
            for (int j = 0; j < 4; j++) {
                const int m = G*4 + j;
                const size_t row = rbase + (size_t)(m * 4);
                const int rloc = wv + m*4;
                #pragma unroll
                for (int t = 0; t < NT; t++) {
                    float s = wave_sum(acc[j][t]);
                    if (lane == 63) {
                        const float e = s + bl[t];
                        outP[row * NT + t] = e;
                        if (t < NC) E_lds[rloc][t] = e;
                    }
                    acc[j][t] = 0.0f;
                }
            }
        }
    }
    #undef ISSUE_PHASE

    __syncthreads();   // E_lds complete

    // ---------------- per-block CRF chunk work (waves specialize) ----------------
    const int sub = bx & 15;    // chunk index within batch
    const int bat = bx >> 4;

    if (wv == 0) {
        // 4 sub-chunks x 8 steps x 5 basis on lanes 0..19
        if (lane < 20) {
            const int sc = lane / 5, basis = lane - sc*5;
            float TR[25];
            #pragma unroll
            for (int j = 0; j < NC; j++)
                #pragma unroll
                for (int k = 0; k < NC; k++) TR[j*5+k] = Tl[j*7+k];
            float fv[5];
            #pragma unroll
            for (int j = 0; j < NC; j++) fv[j] = (j == basis) ? 0.0f : NEGV;
            const int s0 = (sub == 0 && sc == 0) ? 1 : sc*8;  // batch step 0 handled by u
            const int s1 = sc*8 + 8;
            for (int s = s0; s < s1; ++s) {
                float fn[5];
                #pragma unroll
                for (int j = 0; j < NC; j++)
                    fn[j] = lse5(fv[0]+TR[j*5+0], fv[1]+TR[j*5+1], fv[2]+TR[j*5+2],
                                 fv[3]+TR[j*5+3], fv[4]+TR[j*5+4]) + E_lds[s][j];
                #pragma unroll
                for (int j = 0; j < NC; j++) fv[j] = fn[j];
            }
            #pragma unroll
            for (int j = 0; j < NC; j++) Msub[sc*25 + basis*5 + j] = fv[j];
        }
        // combine 4 -> 2 -> 1 (single wave: program order gives LDS ordering)
        if (lane < 50) {
            const int pp = lane / 25, r = lane - pp*25, i = r/5, jj = r - (r/5)*5;
            const float* A = &Msub[(2*pp)*25 + i*5];
            const float* B = &Msub[(2*pp+1)*25 + jj];
            Cb[pp*25 + r] = lse5(A[0]+B[0], A[1]+B[5], A[2]+B[10], A[3]+B[15], A[4]+B[20]);
        }
        if (lane < 25) {
            const int i = lane/5, jj = lane - i*5;
            const float* A = &Cb[i*5];
            const float* B = &Cb[25 + jj];
            ws[WS_M + (size_t)bx*32 + lane] =
                lse5(A[0]+B[0], A[1]+B[5], A[2]+B[10], A[3]+B[15], A[4]+B[20]);
        }
    } else if (wv == 1) {
        // gold partial for this block's 32 tokens
        float g = 0.0f;
        if (lane < 32) {
            const int lg = bx*32 + lane;
            const int t  = lab[lg];
            const int tp = ((lg & (LSEQ-1)) == 0) ? START_TAG : lab[lg - 1];
            g = E_lds[lane][t] + Tl[t*7 + tp];
        }
        float gs = wave_sum(g);
        if (lane == 63) ws[WS_G + bx] = gs;
    } else if (wv == 2) {
        // u injection (batch step 0) from the batch's first block
        if (sub == 0 && lane < NC)
            ws[WS_U + bat*8 + lane] = Tl[lane*7 + START_TAG] + E_lds[0][lane];
    }

    __threadfence();
    cg::this_grid().sync();

    // ---------------- per-batch fold: blocks 0..63, wave 0 ----------------
    if (bx < BSEQ && wv == 0) {
        if (lane < 25) {
            #pragma unroll
            for (int m = 0; m < 16; ++m)
                Mbuf[m*25 + lane] = ws[WS_M + ((size_t)bx*16 + m)*32 + lane];
        }
        float gp = (lane < 16) ? ws[WS_G + bx*16 + lane] : 0.0f;
        float gtot = wave_sum(gp);
        gtot = __shfl(gtot, 63);
        if (lane < NC) {
            const int j = lane;
            float fvr = ws[WS_U + bx*8 + j];
            for (int m = 0; m < 16; ++m) {
                const float f0 = __shfl(fvr, 0), f1 = __shfl(fvr, 1), f2 = __shfl(fvr, 2),
                            f3 = __shfl(fvr, 3), f4 = __shfl(fvr, 4);
                const float* M = &Mbuf[m*25];
                fvr = lse5(f0 + M[0*5+j], f1 + M[1*5+j], f2 + M[2*5+j],
                           f3 + M[3*5+j], f4 + M[4*5+j]);
            }
            const float v0 = __shfl(fvr, 0), v1 = __shfl(fvr, 1), v2 = __shfl(fvr, 2),
                        v3 = __shfl(fvr, 3), v4 = __shfl(fvr, 4);
            if (j == 0) {
                float fwd = lse5(v0 + Tl[STOP_TAG*7+0], v1 + Tl[STOP_TAG*7+1],
                                 v2 + Tl[STOP_TAG*7+2], v3 + Tl[STOP_TAG*7+3],
                                 v4 + Tl[STOP_TAG*7+4]);
                float gold = gtot + Tl[STOP_TAG*7 + lab[bx*LSEQ + LSEQ - 1]];
                atomicAdd(out, fwd - gold);
            }
        }
    }
}

// ================= FALLBACK path (proven R3 two-kernel, 214us) =================
__global__ __launch_bounds__(256)
void k_logits(const float* __restrict__ X, const float* __restrict__ W,
              const float* __restrict__ bvec, const int* __restrict__ lab,
              float* __restrict__ out)
{
    __shared__ float Wl[NT][CCH];
    __shared__ float bl[NT];

    const int lane = threadIdx.x & 63;
    const int wid  = (blockIdx.x * 256 + threadIdx.x) >> 6;
    const int nw   = (GRID_LOGITS * 256) >> 6;

    vfloat4 xb[3][4];

    #define ISSUE_PHASE(p, slot)                                                   \
        if ((p) < 8) {                                                             \
            const int G_ = (p) >> 2, k_ = (p) & 3;                                 \
            _Pragma("unroll")                                                      \
            for (int j = 0; j < 4; j++) {                                          \
                const size_t row_ = (size_t)(wid + (G_*4 + j) * nw);               \
                const vfloat4* xp_ = (const vfloat4*)(X + row_ * CCH) + (k_*64 + lane); \
                xb[slot][j] = __builtin_nontemporal_load(xp_);                     \
            }                                                                      \
        }

    ISSUE_PHASE(0, 0)
    ISSUE_PHASE(1, 1)

    {
        const vfloat4* W4  = (const vfloat4*)W;
        vfloat4*       Wl4 = (vfloat4*)(&Wl[0][0]);
        for (int i = threadIdx.x; i < NT*CCH/4; i += 256) Wl4[i] = W4[i];
        if (threadIdx.x < NT) bl[threadIdx.x] = bvec[threadIdx.x];
    }
    __syncthreads();

    float* outP = out + 1 + NTOK;

    float acc[4][NT];
    #pragma unroll
    for (int j = 0; j < 4; j++)
        #pragma unroll
        for (int t = 0; t < NT; t++) acc[j][t] = 0.0f;

    #pragma unroll
    for (int p = 0; p < 8; ++p) {
        const int slot = p % 3;
        const int k    = p & 3;

        ISSUE_PHASE(p + 2, (p + 2) % 3)

        vfloat4 wreg[NT];
        {
            const int cb = (k*64 + lane) * 4;
            #pragma unroll
            for (int t = 0; t < NT; t++)
                wreg[t] = *(const vfloat4*)(&Wl[t][cb]);
        }

        #pragma unroll
        for (int j = 0; j < 4; j++) {
            #pragma unroll
            for (int t = 0; t < NT; t++) {
                acc[j][t] = fmaf(xb[slot][j].x, wreg[t].x,
                            fmaf(xb[slot][j].y, wreg[t].y,
                            fmaf(xb[slot][j].z, wreg[t].z,
                            fmaf(xb[slot][j].w, wreg[t].w, acc[j][t]))));
            }
        }

        if (k == 3) {
            const int G = p >> 2;
            #pragma unroll
            for (int j = 0; j < 4; j++) {
                const size_t row = (size_t)(wid + (G*4 + j) * nw);
                #pragma unroll
                for (int t = 0; t < NT; t++) {
                    float s = wave_sum(acc[j][t]);
                    if (lane == 63) outP[row * NT + t] = s + bl[t];
                    acc[j][t] = 0.0f;
                }
            }
        }
    }
    #undef ISSUE_PHASE

    for (int i = blockIdx.x * 256 + threadIdx.x; i < NTOK; i += GRID_LOGITS * 256)
        out[1 + i] = (float)lab[i];
    if (blockIdx.x == 0 && threadIdx.x == 0) out[0] = 0.0f;
}

__global__ __launch_bounds__(320)
void k_crf(const float* __restrict__ dout_ro, const int* __restrict__ lab,
           const float* __restrict__ trans, float* __restrict__ score)
{
    __shared__ float E[LSEQ*NT];
    __shared__ float M2[32*25];
    __shared__ float T[49];
    __shared__ float u_sh[NC];
    __shared__ float gred[5];

    const int b   = blockIdx.x;
    const int tid = threadIdx.x;
    const float* feats = dout_ro + 1 + NTOK + (size_t)b * (LSEQ*NT);

    for (int i = tid; i < LSEQ*NT; i += 320) E[i] = feats[i];
    if (tid < 49) T[tid] = trans[tid];
    __syncthreads();

    if (tid < NC) u_sh[tid] = T[tid*NT + START_TAG] + E[tid];

    float g = 0.0f;
    for (int l = tid; l < LSEQ; l += 320) {
        const int t  = lab[b*LSEQ + l];
        const int tp = (l == 0) ? START_TAG : lab[b*LSEQ + l - 1];
        g += E[l*NT + t] + T[t*NT + tp];
    }
    if (tid == 0) g += T[STOP_TAG*NT + lab[b*LSEQ + LSEQ - 1]];
    {
        float gs = wave_sum(g);
        if ((tid & 63) == 63) gred[tid >> 6] = gs;
    }

    float TR[NC*NC];
    #pragma unroll
    for (int j = 0; j < NC; j++)
        #pragma unroll
        for (int k = 0; k < NC; k++) TR[j*NC + k] = T[j*NT + k];

    const int chunk = tid / NC;
    const int basis = tid - chunk * NC;
    float fv[NC];
    #pragma unroll
    for (int j = 0; j < NC; j++) fv[j] = (j == basis) ? 0.0f : NEGV;

    const int l0    = (chunk == 0) ? 1 : chunk * 8;
    const int steps = (chunk == 0) ? 7 : 8;
    for (int s = 0; s < steps; s++) {
        const int l = l0 + s;
        float fn[NC];
        #pragma unroll
        for (int j = 0; j < NC; j++) {
            fn[j] = lse5(fv[0] + TR[j*NC+0], fv[1] + TR[j*NC+1], fv[2] + TR[j*NC+2],
                         fv[3] + TR[j*NC+3], fv[4] + TR[j*NC+4]) + E[l*NT + j];
        }
        #pragma unroll
        for (int j = 0; j < NC; j++) fv[j] = fn[j];
    }
    __syncthreads();
    #pragma unroll
    for (int j = 0; j < NC; j++) E[chunk*25 + basis*NC + j] = fv[j];

    int n = 64, cur = 0;
    while (n > 1) {
        __syncthreads();
        const float* in = (cur == 0) ? (const float*)E : (const float*)M2;
        float*       ob = (cur == 0) ? M2 : E;
        const int half = n >> 1;
        for (int e2 = tid; e2 < half*25; e2 += 320) {
            const int p = e2 / 25, r = e2 - p*25;
            const int i = r / NC, j = r - (r/NC)*NC;
            const float* A  = in + (2*p)*25 + i*NC;
            const float* Bm = in + (2*p + 1)*25 + j;
            ob[p*25 + r] = lse5(A[0] + Bm[0], A[1] + Bm[NC], A[2] + Bm[2*NC],
                                A[3] + Bm[3*NC], A[4] + Bm[4*NC]);
        }
        cur ^= 1; n = half;
    }
    __syncthreads();

    if (tid == 0) {
        float gg = gred[0] + gred[1] + gred[2] + gred[3] + gred[4];
        const float* M = (cur == 0) ? (const float*)E : (const float*)M2;
        float v[NC];
        #pragma unroll
        for (int j = 0; j < NC; j++)
            v[j] = lse5(u_sh[0] + M[0*NC+j], u_sh[1] + M[1*NC+j], u_sh[2] + M[2*NC+j],
                        u_sh[3] + M[3*NC+j], u_sh[4] + M[4*NC+j]);
        float fwd = lse5(v[0] + T[STOP_TAG*NT+0], v[1] + T[STOP_TAG*NT+1],
                         v[2] + T[STOP_TAG*NT+2], v[3] + T[STOP_TAG*NT+3],
                         v[4] + T[STOP_TAG*NT+4]);
        atomicAdd(score, fwd - gg);
    }
}

extern "C" void kernel_launch(void* const* d_in, const int* in_sizes, int n_in,
                              void* d_out, int out_size, void* d_ws, size_t ws_size,
                              hipStream_t stream) {
    const float* X     = (const float*)d_in[0];   // fuse_embeddings [32768,1024]
    const int*   lab   = (const int*)  d_in[1];   // label_class [32768]
    const float* W     = (const float*)d_in[2];   // [7,1024]
    const float* bvec  = (const float*)d_in[3];   // [7]
    const float* trans = (const float*)d_in[4];   // [7,7]
    float* out = (float*)d_out;
    float* wsf = (float*)d_ws;

    // Coop path needs 4 blocks/CU co-residency (VGPR<=128) and workspace.
    int maxB = 0;
    hipError_t oe = hipOccupancyMaxActiveBlocksPerMultiprocessor(&maxB, k_fused, FBLK, 0);
    if (oe == hipSuccess && maxB >= 4 && wsf != nullptr &&
        ws_size >= (size_t)WS_TOT * sizeof(float)) {
        void* kargs[] = {(void*)&X, (void*)&W, (void*)&bvec, (void*)&lab,
                         (void*)&trans, (void*)&out, (void*)&wsf};
        hipError_t le = hipLaunchCooperativeKernel((const void*)k_fused,
                                                   dim3(FGRID), dim3(FBLK),
                                                   kargs, 0, stream);
        if (le == hipSuccess) return;
    }

    // Fallback: proven two-kernel path
    k_logits<<<GRID_LOGITS, 256, 0, stream>>>(X, W, bvec, lab, out);
    k_crf<<<BSEQ, 320, 0, stream>>>(out, lab, trans, out);
}